// Round 2
// baseline (132.226 us; speedup 1.0000x reference)
//
#include <hip/hip_runtime.h>

// AdjGAT: V=20000, D=256, K=16, O=128, H=4.
// Math: attn[h,v] = x[v].(W_h a_h);  out[v] = relu( (1/H)[ sum_h (sum_k c_hk x[nbr_k]).W_h + sum_h b_h ] )
// R11 == R10 resubmit (R10 bench died in infra: "container failed twice", no signal).
// R10: split fused gat (45us, MfmaUtil 4%, occ 26%, latency-bound) into:
//   KC1 agg:  gather+softmax-weighted sum at HIGH occupancy (32-reg accum/lane,
//             512thr/16 nodes, launch_bounds(512,6) -> target <=85 VGPR, ~24 waves/CU).
//             y bounced through XOR-swizzled LDS, streamed to global COALESCED in
//             exact MFMA A-frag order (41MB fp16).
//   KC2 gemm: pure dense frag GEMM [V x 1024]x[1024 x 128]; A-frags + B-frags are
//             contiguous 1KB global reads, no LDS, no barriers, no gather.
//             32 nodes/block (grid 625): Wt L2 re-read halves vs old P3.
// Pipeline (4 launches):
//   KA prep:   Wt fp16 B-frag order + wt[h][d] = sum_o W*a
//   KB xsplit: xh = fp16(x); attn4[v][h] (fused)
//   KC1 agg:   softmax coefs + y = sum_k c*x  -> yg (frag order)
//   KC2 gemm:  out = relu(0.25*(yg.Wt + bbar))
// ws: attn4 0.32MB | xh 10.24MB | Wt 0.26MB | wt 4KB | yg 40.96MB (~51.8MB; arena 256MiB)

#define V_N 20000
#define D_N 256
#define K_N 16
#define O_N 128
#define H_N 4
#define NEG_INF -1e9f

typedef _Float16 f16x8 __attribute__((ext_vector_type(8)));
typedef _Float16 f16x4 __attribute__((ext_vector_type(4)));
typedef float    f32x4 __attribute__((ext_vector_type(4)));

// ---------------- KA: prep_w (B-frag swizzle) + wtilde, fused ----------------
__global__ __launch_bounds__(256) void prep_kernel(
    const float* __restrict__ W, const float* __restrict__ a,
    _Float16* __restrict__ Wt, float* __restrict__ wt)
{
    if (blockIdx.x < 64) {
        const int idx  = blockIdx.x * 256 + threadIdx.x;  // 16384 frag-lane slots
        const int lane = idx & 63;
        const int nt   = (idx >> 6) & 7;    // col tile (16 cols)
        const int s    = (idx >> 9) & 7;    // k slice (32 chans)
        const int h    = idx >> 12;
        const int o    = nt * 16 + (lane & 15);
        const int d0   = s * 32 + (lane >> 4) * 8;
        f16x8 v;
        #pragma unroll
        for (int j = 0; j < 8; ++j)
            v[j] = (_Float16)W[((size_t)h * D_N + d0 + j) * O_N + o];
        *(f16x8*)&Wt[(size_t)idx * 8] = v;
    } else {
        const int h = blockIdx.x - 64;
        const int d = threadIdx.x;
        const float* Wrow = W + ((size_t)h * D_N + d) * O_N;
        const float* ah   = a + h * O_N;
        float s = 0.f;
        #pragma unroll
        for (int o = 0; o < O_N; o += 4) {
            const float4 wv = *(const float4*)&Wrow[o];
            const float4 av = *(const float4*)&ah[o];
            s = fmaf(wv.x, av.x, s); s = fmaf(wv.y, av.y, s);
            s = fmaf(wv.z, av.z, s); s = fmaf(wv.w, av.w, s);
        }
        wt[h * D_N + d] = s;
    }
}

// ---------------- KB: x -> fp16 copy + fused attn logits ----------------
__global__ __launch_bounds__(256) void xsplit_attn_kernel(
    const float* __restrict__ x, const float* __restrict__ wt,
    _Float16* __restrict__ xh, float* __restrict__ attn4)
{
    const int wid  = threadIdx.x >> 6;
    const int lane = threadIdx.x & 63;
    const int v    = blockIdx.x * 4 + wid;

    const float4 p = *(const float4*)&x[(size_t)v * D_N + lane * 4];
    f16x4 hv = { (_Float16)p.x, (_Float16)p.y, (_Float16)p.z, (_Float16)p.w };
    *(f16x4*)&xh[(size_t)v * D_N + lane * 4] = hv;

    float s[H_N];
    #pragma unroll
    for (int h = 0; h < H_N; ++h) {
        const float4 w = *(const float4*)&wt[h * D_N + lane * 4];
        float t = fmaf(p.x, w.x, 0.f);
        t = fmaf(p.y, w.y, t); t = fmaf(p.z, w.z, t); t = fmaf(p.w, w.w, t);
        s[h] = t;
    }
    #pragma unroll
    for (int h = 0; h < H_N; ++h)
        #pragma unroll
        for (int dd = 32; dd >= 1; dd >>= 1)
            s[h] += __shfl_xor(s[h], dd);
    if (lane == 0)
        *(float4*)&attn4[(size_t)v * 4] = make_float4(s[0], s[1], s[2], s[3]);
}

// ---------------- KC1: softmax coefs + gather + weighted sum -> yg -----------
// Block = 16 nodes (one MFMA m-tile), 512 threads = 8 waves.
// Wave w owns nodes {2w, 2w+1}: half-wave hw = node parity, lane sl = d-chunk.
// y accum: 4 heads x 8 ch = 32 f32 regs/lane (vs 64 in fused shape).
// yg layout: frag(mt, S)=contiguous 1KB, S = h*8+s (k = h*256+d), lane slot l*16B:
//   A[m = l&15][k-chunk q = l>>4], exactly the 16x16x32 A-fragment order.
__global__ __launch_bounds__(512, 6) void agg_kernel(
    const _Float16* __restrict__ xh, const float* __restrict__ attn4,
    const int* __restrict__ adj, const int* __restrict__ mask_p,
    _Float16* __restrict__ yg)
{
    const int v0  = blockIdx.x * 16;
    const int tid = threadIdx.x;

    __shared__ int      sidx_s[16][17];          // +1 pad
    __shared__ float    coefs_s[K_N][17][H_N];   // [k][node(+pad)][h]
    // yl slot (f16x8 units): h*512 + n*32 + (sl ^ n)  (proven <=2-way pattern)
    __shared__ _Float16 yl[H_N * 512 * 8];       // 32KB

    // ---- P1: softmax coefs, threads 0..255 = (node, k) ----
    if (tid < 256) {
        const int node = tid >> 4;
        const int k    = tid & 15;
        const int mask = mask_p[0];
        const int idx  = adj[(v0 + node) * K_N + k];
        const bool pad = (idx >= mask);
        const int safe = pad ? 0 : idx;
        const float4 av = *(const float4*)&attn4[(size_t)safe * 4];
        const float lg[H_N] = { pad ? NEG_INF : av.x, pad ? NEG_INF : av.y,
                                pad ? NEG_INF : av.z, pad ? NEG_INF : av.w };
        float c[H_N];
        #pragma unroll
        for (int h = 0; h < H_N; ++h) {
            float mx = lg[h];
            #pragma unroll
            for (int s2 = 8; s2 >= 1; s2 >>= 1)
                mx = fmaxf(mx, __shfl_xor(mx, s2, 16));
            const float e = pad ? 0.f : __expf(lg[h] - mx);
            float sum = e;
            #pragma unroll
            for (int s2 = 8; s2 >= 1; s2 >>= 1)
                sum += __shfl_xor(sum, s2, 16);
            // pad coef 0 == ref; all-pad row -> y=0 -> relu(bbar)
            c[h] = pad ? 0.f : e / sum;
        }
        *(float4*)&coefs_s[k][node][0] = make_float4(c[0], c[1], c[2], c[3]);
        sidx_s[node][k] = safe;
    }
    __syncthreads();

    // ---- P2: gather + weighted accumulate (no barriers inside) ----
    const int w    = tid >> 6;
    const int lane = tid & 63;
    const int hw   = lane >> 5;        // node parity within wave
    const int sl   = lane & 31;        // 16B slot within 512B row
    const int ln   = w * 2 + hw;       // local node 0..15

    float y[H_N][8];
    #pragma unroll
    for (int h = 0; h < H_N; ++h)
        #pragma unroll
        for (int j = 0; j < 8; ++j) y[h][j] = 0.f;

    const _Float16* xsl = xh + sl * 8;
    #pragma unroll 2
    for (int k = 0; k < K_N; ++k) {
        const int si = sidx_s[ln][k];
        const f16x8 xv = *(const f16x8*)&xsl[(size_t)si * D_N];
        const float4 cc = *(const float4*)&coefs_s[k][ln][0];
        const float ch4[H_N] = { cc.x, cc.y, cc.z, cc.w };
        #pragma unroll
        for (int h = 0; h < H_N; ++h)
            #pragma unroll
            for (int j = 0; j < 8; ++j)
                y[h][j] = fmaf(ch4[h], (float)xv[j], y[h][j]);
    }

    // fp16 A-fragments into LDS, XOR-swizzled (conflict-free per 8-lane group)
    {
        const int slot = ln * 32 + (sl ^ ln);
        #pragma unroll
        for (int h = 0; h < H_N; ++h) {
            f16x8 v;
            #pragma unroll
            for (int j = 0; j < 8; ++j) v[j] = (_Float16)y[h][j];
            *(f16x8*)&yl[(size_t)(h * 512 + slot) * 8] = v;
        }
    }
    __syncthreads();

    // ---- P3: stream LDS -> global in frag order, fully coalesced ----
    {
        const int s = tid >> 6;        // k-slice within head, 0..7
        const int m = lane & 15;
        const int q = lane >> 4;
        _Float16* ygb = yg + (size_t)blockIdx.x * (32 * 512);
        #pragma unroll
        for (int h = 0; h < H_N; ++h) {
            const int rs = m * 32 + ((((s << 2) | q)) ^ m);
            const f16x8 v = *(const f16x8*)&yl[(size_t)(h * 512 + rs) * 8];
            *(f16x8*)&ygb[((size_t)(h * 8 + s) * 64 + lane) * 8] = v;
        }
    }
}

// ---------------- KC2: dense frag GEMM  out = relu(0.25*(yg.Wt + bbar)) -----
// Block = 2 m-tiles (32 nodes), 4 waves: wave = (m-tile, col-half of 4 tiles).
// Grid 625 (= 1250 m-tiles exactly). A-frags and B-frags are contiguous 1KB
// global loads; B shared across waves via L1. No LDS, no syncthreads.
__global__ __launch_bounds__(256, 6) void gemm_kernel(
    const _Float16* __restrict__ yg, const _Float16* __restrict__ Wt,
    const float* __restrict__ b, float* __restrict__ out)
{
    const int w    = threadIdx.x >> 6;
    const int lane = threadIdx.x & 63;
    const int mt   = blockIdx.x * 2 + (w >> 1);
    const int nth  = (w & 1) * 4;            // first of this wave's 4 col tiles

    const _Float16* Ab = yg + (size_t)mt * (32 * 512) + lane * 8;
    const _Float16* Bb = Wt + (size_t)nth * 512 + lane * 8;

    f32x4 acc[4];
    #pragma unroll
    for (int nt = 0; nt < 4; ++nt) acc[nt] = (f32x4){0.f, 0.f, 0.f, 0.f};

    #pragma unroll 2
    for (int S = 0; S < 32; ++S) {           // k-slice over h*256+d
        const f16x8 af = *(const f16x8*)&Ab[(size_t)S * 512];
        #pragma unroll
        for (int nt = 0; nt < 4; ++nt) {
            const f16x8 bf = *(const f16x8*)&Bb[(size_t)(S * 8 + nt) * 512];
            acc[nt] = __builtin_amdgcn_mfma_f32_16x16x32_f16(af, bf, acc[nt], 0, 0, 0);
        }
    }

    // epilogue: mean heads + mean bias + relu; C: col=lane&15, row=(lane>>4)*4+r
    const int m  = lane & 15;
    const int q  = lane >> 4;
    const int vb = mt * 16;
    #pragma unroll
    for (int nt = 0; nt < 4; ++nt) {
        const int col = (nth + nt) * 16 + m;
        const float bb = b[col] + b[O_N + col] + b[2 * O_N + col] + b[3 * O_N + col];
        #pragma unroll
        for (int r = 0; r < 4; ++r) {
            const int v = vb + q * 4 + r;
            out[(size_t)v * O_N + col] = fmaxf(0.25f * (acc[nt][r] + bb), 0.f);
        }
    }
}

extern "C" void kernel_launch(void* const* d_in, const int* in_sizes, int n_in,
                              void* d_out, int out_size, void* d_ws, size_t ws_size,
                              hipStream_t stream) {
    const float* x      = (const float*)d_in[0];
    const float* W      = (const float*)d_in[1];
    const float* a      = (const float*)d_in[2];
    const float* b      = (const float*)d_in[3];
    const int*   adj    = (const int*)d_in[4];
    const int*   mask_p = (const int*)d_in[5];
    float*       out    = (float*)d_out;

    // ws layout (bytes)
    char* p = (char*)d_ws;
    float*    attn4 = (float*)p;                     //    320,000
    _Float16* xh    = (_Float16*)(p + 320000);       // 10,240,000
    _Float16* Wt    = (_Float16*)(p + 10560000);     //    262,144
    float*    wt    = (float*)(p + 10822144);        //      4,096
    _Float16* yg    = (_Float16*)(p + 10826240);     // 40,960,000 (1250 mt x 32KB)

    prep_kernel<<<68, 256, 0, stream>>>(W, a, Wt, wt);
    xsplit_attn_kernel<<<V_N / 4, 256, 0, stream>>>(x, wt, xh, attn4);
    agg_kernel<<<V_N / 16, 512, 0, stream>>>(xh, attn4, adj, mask_p, yg);
    gemm_kernel<<<V_N / 32, 256, 0, stream>>>(yg, Wt, b, out);
}